// Round 1
// 2774.923 us; speedup vs baseline: 1.3720x; 1.3720x over previous
//
#include <hip/hip_runtime.h>

typedef unsigned short ushort_t;
typedef unsigned int   uint_t;
typedef __attribute__((ext_vector_type(8))) short short8;
typedef __attribute__((ext_vector_type(4))) float floatx4;

#define NEGV -1000000000.0f

__device__ __forceinline__ float bf2f(ushort_t h){ return __uint_as_float(((uint_t)h)<<16); }
__device__ __forceinline__ ushort_t f2bf(float f){
  uint_t u = __float_as_uint(f);
  uint_t r = u + 0x7fffu + ((u>>16)&1u);
  return (ushort_t)(r>>16);
}
__device__ __forceinline__ float wredsum(float v){ for(int o=32;o;o>>=1) v += __shfl_xor(v,o); return v; }
__device__ __forceinline__ float wredmax(float v){ for(int o=32;o;o>>=1) v = fmaxf(v,__shfl_xor(v,o)); return v; }
__device__ __forceinline__ int   wredsumi(int v){ for(int o=32;o;o>>=1) v += __shfl_xor(v,o); return v; }

// ---------------------------------------------------------------------------
// dtype-adaptive conversion, vectorized x8. Probe once per block in wave 0.
// ---------------------------------------------------------------------------
__global__ void k_cvt8(const void* __restrict__ src, ushort_t* __restrict__ dst,
                       long n, const ushort_t* __restrict__ probe_src){
  __shared__ int sflag;
  if (threadIdx.x < 64){
    ushort_t u = probe_src[2*threadIdx.x];
    int e = (u>>7)&0xFF;
    int c = (e>=100 && e<=140) ? 1 : 0;
    c = wredsumi(c);
    if (threadIdx.x==0) sflag = (c>32) ? 1 : 0;
  }
  __syncthreads();
  bool isbf = (sflag!=0);
  long base = (blockIdx.x*256L + threadIdx.x)*8;
  if (base>=n) return;
  if (isbf){
    if (base+8<=n) *(uint4*)(dst+base) = *(const uint4*)((const ushort_t*)src+base);
    else for (long i=base;i<n;i++) dst[i]=((const ushort_t*)src)[i];
  } else {
    const float* s = (const float*)src;
    if (base+8<=n){
      float4 v0 = *(const float4*)(s+base);
      float4 v1 = *(const float4*)(s+base+4);
      ushort_t o[8] = {f2bf(v0.x),f2bf(v0.y),f2bf(v0.z),f2bf(v0.w),
                       f2bf(v1.x),f2bf(v1.y),f2bf(v1.z),f2bf(v1.w)};
      *(uint4*)(dst+base) = *(uint4*)o;
    } else {
      for (long i=base;i<n;i++) dst[i]=f2bf(s[i]);
    }
  }
}

__device__ __forceinline__ bool probe_is_bf16(const ushort_t* probe_src){
  int c=0;
  #pragma unroll 1
  for (int i=0;i<64;i++){
    ushort_t u = probe_src[2*i];
    int e = (u>>7)&0xFF;
    c += (e>=100 && e<=140) ? 1 : 0;
  }
  return c>32;
}

// ---------------------------------------------------------------------------
// small prep kernels
// ---------------------------------------------------------------------------
__global__ void k_lens(const int* __restrict__ ti, const int* __restrict__ li,
                       int* __restrict__ nonpad, int* __restrict__ text_len,
                       int* __restrict__ left_len){
  int b = blockIdx.x, t = threadIdx.x;
  nonpad[b*128+t] = (ti[b*128+t]!=0) ? 1 : 0;
  if (t==0){
    int c=0; for (int k2=0;k2<128;k2++) c += (ti[b*128+k2]!=0);
    text_len[b]=c;
    int l=0; for (int k2=0;k2<24;k2++) l += (li[b*24+k2]!=0);
    left_len[b]=l;
  }
}

__global__ void k_aspmean(const int* __restrict__ ai, const ushort_t* __restrict__ em,
                          float* __restrict__ asp_mean){
  int b = blockIdx.x;
  int idxs[5]; int cnt=0;
  for (int a=0;a<5;a++){ int ix=ai[b*5+a]; idxs[a]=ix; cnt += (ix!=0); }
  float inv = 1.0f/(float)cnt;
  for (int d=threadIdx.x; d<300; d+=128){
    float s=0.f;
    for (int a=0;a<5;a++) if (idxs[a]) s += bf2f(em[(long)idxs[a]*300+d]);
    asp_mean[b*300+d] = s*inv;
  }
}

__global__ void k_embs(const int* __restrict__ ti, const int* __restrict__ pi,
                       const int* __restrict__ asp_post,
                       const ushort_t* __restrict__ em, const ushort_t* __restrict__ pe,
                       const float* __restrict__ asp_mean, ushort_t* __restrict__ embs){
  int blk = blockIdx.x;
  int b = blk>>7, t = blk&127;
  int ap = asp_post[b];
  int tix = ti[b*128+t];
  int pix = pi[b*128+t];
  for (int col=threadIdx.x; col<336; col+=128){
    ushort_t v;
    if (col<300) v = (t==ap) ? f2bf(asp_mean[b*300+col]) : em[(long)tix*300+col];
    else if (col<330) v = pe[pix*30 + (col-300)];
    else v = 0;
    embs[(long)(b*128+t)*336 + col] = v;
  }
}

__global__ void k_padcopy(const ushort_t* __restrict__ src, ushort_t* __restrict__ dst,
                          int rows, int sk, int dk){
  int i = blockIdx.x*blockDim.x + threadIdx.x;
  int n = rows*dk;
  if (i<n){
    int r = i/dk, c2 = i - r*dk;
    dst[i] = (c2<sk) ? src[r*sk+c2] : 0;
  }
}

// Whh repack for reg-resident LSTM: dst[1280][320] bf16, row' = j*4 + gate
// (j padded 300->320, K 300->320, zeros elsewhere). src row = gate*300 + j.
__global__ void k_padwhh2(const ushort_t* __restrict__ src, ushort_t* __restrict__ dst){
  int i = blockIdx.x*blockDim.x + threadIdx.x;
  if (i >= 1280*320) return;
  int r = i/320, k = i - r*320;
  int j = r>>2, gate = r&3;
  ushort_t v = 0;
  if (j<300 && k<300) v = src[(long)(gate*300+j)*300 + k];
  dst[i] = v;
}

__global__ void k_biassum(const ushort_t* __restrict__ a, const ushort_t* __restrict__ b,
                          float* __restrict__ dst, int n){
  int i = blockIdx.x*blockDim.x + threadIdx.x;
  if (i<n) dst[i] = bf2f(a[i]) + bf2f(b[i]);
}
__global__ void k_biascvt(const ushort_t* __restrict__ a, float* __restrict__ dst, int n){
  int i = blockIdx.x*blockDim.x + threadIdx.x;
  if (i<n) dst[i] = bf2f(a[i]);
}

// ---------------------------------------------------------------------------
// generic bf16 MFMA GEMM: 128x128 tile, 4 waves (2x2), each 64x64 via 4x4
// frags of 16x16x32.  TB=1: C = A * B^T.  TB=0: C = A * B.
// MODE 1: bf16 store (opt bias/relu/rowscale)
// MODE 2: qk head-scatter bf16 store (bias), T=128, dk=100->104
// MODE 3: f32 store, *0.1 and nonpad column mask (attention scores)
// MODE 4: gi gate-packed scatter: row=(b,t), col=(gate,jj) ->
//         gip[((t*320+jj)*128+b)*4+gate]  (bf16, for lstm2_k)
// ---------------------------------------------------------------------------
template<int TB, int MODE>
__global__ __launch_bounds__(256) void gemm_k(
    int M, int N, int K,
    const ushort_t* __restrict__ A, long lda, long sAz,
    const ushort_t* __restrict__ B, long ldb, long sBz,
    float* __restrict__ Cf, ushort_t* __restrict__ Cb, long ldc, long sCz,
    const float* __restrict__ bias, int relu,
    const float* __restrict__ rowscale,
    const int* __restrict__ nonpad)
{
  __shared__ ushort_t As[128*40];
  __shared__ ushort_t Bs[128*40];
  const int tid = threadIdx.x;
  const int m0 = blockIdx.x*128, n0 = blockIdx.y*128;
  const int z = blockIdx.z;
  const ushort_t* Ap = A + (long)z*sAz;
  const ushort_t* Bp = B + (long)z*sBz;
  floatx4 acc[4][4];
  #pragma unroll
  for (int i=0;i<4;i++)
    #pragma unroll
    for (int j=0;j<4;j++){ acc[i][j][0]=0.f; acc[i][j][1]=0.f; acc[i][j][2]=0.f; acc[i][j][3]=0.f; }
  const int w = tid>>6, wm = w&1, wn = w>>1;
  const int lane = tid&63, lr = lane&15, lq = lane>>4;

  for (int k0=0;k0<K;k0+=32){
    #pragma unroll
    for (int c2=0;c2<2;c2++){
      int ch = tid + 256*c2;
      int row = ch>>2, kc = (ch&3)*8;
      int gr = m0+row, gk = k0+kc;
      uint4 v{};
      if (gr<M && gk<K) v = *(const uint4*)(Ap + (long)gr*lda + gk);
      *(uint4*)(&As[row*40+kc]) = v;
    }
    if (TB){
      #pragma unroll
      for (int c2=0;c2<2;c2++){
        int ch = tid + 256*c2;
        int row = ch>>2, kc = (ch&3)*8;
        int gn = n0+row, gk = k0+kc;
        uint4 v{};
        if (gn<N && gk<K) v = *(const uint4*)(Bp + (long)gn*ldb + gk);
        int sw = kc ^ (((row>>3)&3)<<3);
        *(uint4*)(&Bs[row*40+sw]) = v;
      }
    } else {
      #pragma unroll
      for (int c2=0;c2<2;c2++){
        int ch = tid + 256*c2;
        int kk = ch>>4, nc = (ch&15)*8;
        int gk = k0+kk, gn = n0+nc;
        uint4 v{};
        if (gk<K && gn<N) v = *(const uint4*)(Bp + (long)gk*ldb + gn);
        uint_t wsv[4] = {v.x, v.y, v.z, v.w};
        #pragma unroll
        for (int e=0;e<8;e++){
          ushort_t hv = (e&1) ? (ushort_t)(wsv[e>>1]>>16) : (ushort_t)(wsv[e>>1]&0xffffu);
          int n = nc+e;
          int sw = kk ^ (((n>>3)&3)<<3);
          Bs[n*40+sw] = hv;
        }
      }
    }
    __syncthreads();
    short8 af[4], bfv[4];
    #pragma unroll
    for (int i=0;i<4;i++) af[i] = *(const short8*)(&As[(wm*64+i*16+lr)*40 + lq*8]);
    #pragma unroll
    for (int j=0;j<4;j++){
      int n = wn*64+j*16+lr;
      int sw = (lq*8) ^ (((n>>3)&3)<<3);
      bfv[j] = *(const short8*)(&Bs[n*40+sw]);
    }
    #pragma unroll
    for (int i=0;i<4;i++)
      #pragma unroll
      for (int j=0;j<4;j++)
        acc[i][j] = __builtin_amdgcn_mfma_f32_16x16x32_bf16(af[i], bfv[j], acc[i][j], 0,0,0);
    __syncthreads();
  }

  #pragma unroll
  for (int i=0;i<4;i++){
    #pragma unroll
    for (int j=0;j<4;j++){
      #pragma unroll
      for (int r=0;r<4;r++){
        int row = m0 + wm*64 + i*16 + lq*4 + r;
        int col = n0 + wn*64 + j*16 + lr;
        if (row<M && col<N){
          float v = acc[i][j][r];
          if (rowscale) v *= rowscale[(long)z*M + row];
          if (bias) v += bias[col];
          if (relu && v<0.f) v = 0.f;
          if (MODE==1){
            Cb[(long)z*sCz + (long)row*ldc + col] = f2bf(v);
          } else if (MODE==2){
            int b = row>>7, t = row&127;
            int h = col/100, d = col - h*100;
            Cb[ ((long)((b*6+h)*128+t))*104 + d ] = f2bf(v);
          } else if (MODE==3){
            v *= 0.1f;
            if (!nonpad[(z/6)*128 + col]) v = NEGV;
            Cf[(long)z*sCz + (long)row*ldc + col] = v;
          } else if (MODE==4){
            int b = row>>7, t = row&127;
            int gate = col/300, jj = col - gate*300;
            Cb[ (((long)t*320 + (long)jj)*128 + b)*4 + gate ] = f2bf(v);
          }
        }
      }
    }
  }
}

// ---------------------------------------------------------------------------
// Register-resident BiLSTM.
// Grid: 40 blocks = 2 dirs x 10 j-slices(32 hidden each) x 2 batch-halves(64).
// Block: 256 threads = 4 waves (1/SIMD, ~280 VGPR budget via launch_bounds).
// Each wave holds its Whh slice (4 Mtiles x 10 kfrags = 160 VGPRs) in
// registers for ALL 128 steps: zero A-traffic in the recurrence.
// A rows packed as j*4+gate, so the 16x16 C layout (row=lq*4+r) gives each
// lane the 4 gate pre-activations of one (j,b) in one floatx4 -> the cell
// update is lane-local; c and h persist in registers.
// h is exchanged per step via a ping-pong global buffer + per-group
// (dir,half) 10-block barrier: __threadfence (release, L2 wb) -> agent-scope
// atomicAdd -> spin -> __threadfence (acquire, L1/L2 inv).
// gi comes pre-packed [t][jj][b][4 gates] (GEMM MODE 4): one 8B load/(j,b).
// ---------------------------------------------------------------------------
__global__ __launch_bounds__(256,1) void lstm2_k(
    const ushort_t* __restrict__ whh2f, const ushort_t* __restrict__ whh2b,
    const ushort_t* __restrict__ gipf, const ushort_t* __restrict__ gipb,
    ushort_t* __restrict__ hbuf,          // [2 dir][2 buf][128 b][320] bf16
    int* __restrict__ barr,               // [4 grp][128 step]
    ushort_t* __restrict__ text_out, const int* __restrict__ text_len)
{
  const int bx = blockIdx.x;
  const int slice = bx % 10;
  const int grp   = bx / 10;              // 0..3 = (bh<<1)|dir
  const int dir = grp & 1, bh = grp >> 1;
  const ushort_t* __restrict__ whh = dir ? whh2b : whh2f;
  const ushort_t* __restrict__ gip = dir ? gipb : gipf;
  ushort_t* hb = hbuf + (long)dir * (2L*128*320);
  int* bar = barr + grp*128;

  const int tid = threadIdx.x;
  const int w = tid>>6, lane = tid&63, lr = lane&15, lq = lane>>4;
  const int wm = w&1, wn = w>>1;          // wave grid: 2 Mgroups x 2 Ngroups

  // ---- Whh slice -> registers (once) ----
  short8 a[4][10];
  #pragma unroll
  for (int mi=0;mi<4;mi++){
    const ushort_t* ar = whh + (long)(slice*128 + (wm*4+mi)*16 + lr)*320 + lq*8;
    #pragma unroll
    for (int kf=0;kf<10;kf++) a[mi][kf] = *(const short8*)(ar + kf*32);
  }

  // ---- lane-owned (jj, b) pairs ----
  int jj_[4], b_[2], tl_[2];
  #pragma unroll
  for (int mi=0;mi<4;mi++) jj_[mi] = slice*32 + (wm*4+mi)*4 + lq;
  #pragma unroll
  for (int ni=0;ni<2;ni++){ b_[ni] = bh*64 + (wn*2+ni)*16 + lr; tl_[ni] = text_len[b_[ni]]; }

  float    c_st[4][2];
  ushort_t h_st[4][2];
  #pragma unroll
  for (int mi=0;mi<4;mi++){ c_st[mi][0]=0.f; c_st[mi][1]=0.f; h_st[mi][0]=0; h_st[mi][1]=0; }

  for (int s=0; s<128; s++){
    const int t = dir ? (127-s) : s;
    const ushort_t* rb = hb + (long)(s&1)*(128L*320);
    ushort_t*       wb = hb + (long)((s+1)&1)*(128L*320);

    // gi prefetch (gates packed x4 -> 8B per (jj,b)); overlaps MFMA phase
    uint2 gp[4][2];
    #pragma unroll
    for (int mi=0;mi<4;mi++)
      #pragma unroll
      for (int ni=0;ni<2;ni++)
        gp[mi][ni] = *(const uint2*)(gip + (((long)t*320 + jj_[mi])*128 + b_[ni])*4);

    // G = Whh_slice @ h : B-frags straight from the coherent h buffer
    floatx4 acc[4][2];
    #pragma unroll
    for (int mi=0;mi<4;mi++)
      #pragma unroll
      for (int ni=0;ni<2;ni++){ acc[mi][ni][0]=0.f; acc[mi][ni][1]=0.f; acc[mi][ni][2]=0.f; acc[mi][ni][3]=0.f; }

    short8 b0[2], b1[2];
    #pragma unroll
    for (int ni=0;ni<2;ni++) b0[ni] = *(const short8*)(rb + (long)b_[ni]*320 + lq*8);
    #pragma unroll
    for (int kf=0;kf<10;kf++){
      if (kf<9){
        #pragma unroll
        for (int ni=0;ni<2;ni++) b1[ni] = *(const short8*)(rb + (long)b_[ni]*320 + (kf+1)*32 + lq*8);
      }
      #pragma unroll
      for (int mi=0;mi<4;mi++)
        #pragma unroll
        for (int ni=0;ni<2;ni++)
          acc[mi][ni] = __builtin_amdgcn_mfma_f32_16x16x32_bf16(a[mi][kf], b0[ni], acc[mi][ni], 0,0,0);
      if (kf<9){
        #pragma unroll
        for (int ni=0;ni<2;ni++) b0[ni] = b1[ni];
      }
    }

    // lane-local cell update
    #pragma unroll
    for (int mi=0;mi<4;mi++){
      #pragma unroll
      for (int ni=0;ni<2;ni++){
        float g_i = acc[mi][ni][0] + bf2f((ushort_t)(gp[mi][ni].x & 0xffffu));
        float g_f = acc[mi][ni][1] + bf2f((ushort_t)(gp[mi][ni].x >> 16));
        float g_g = acc[mi][ni][2] + bf2f((ushort_t)(gp[mi][ni].y & 0xffffu));
        float g_o = acc[mi][ni][3] + bf2f((ushort_t)(gp[mi][ni].y >> 16));
        float ig = 1.f/(1.f+expf(-g_i));
        float fg = 1.f/(1.f+expf(-g_f));
        float gg = tanhf(g_g);
        float og = 1.f/(1.f+expf(-g_o));
        float cn = fg*c_st[mi][ni] + ig*gg;
        float hn = og*tanhf(cn);
        bool m = (t < tl_[ni]);
        if (m) c_st[mi][ni] = cn;
        ushort_t hv = m ? f2bf(hn) : h_st[mi][ni];
        h_st[mi][ni] = hv;
        if (jj_[mi] < 300){
          wb[(long)b_[ni]*320 + jj_[mi]] = hv;
          text_out[((long)(b_[ni]*128 + t))*600 + dir*300 + jj_[mi]] = m ? f2bf(hn) : (ushort_t)0;
        }
      }
    }

    // per-(dir,half) 10-block barrier with device-scope coherence
    __syncthreads();                               // drains this block's stores (vmcnt 0)
    if (tid==0){
      __threadfence();                             // release: L2 writeback to L3
      __hip_atomic_fetch_add(&bar[s], 1, __ATOMIC_RELAXED, __HIP_MEMORY_SCOPE_AGENT);
      while (__hip_atomic_load(&bar[s], __ATOMIC_RELAXED, __HIP_MEMORY_SCOPE_AGENT) < 10)
        __builtin_amdgcn_s_sleep(1);
      __threadfence();                             // acquire: L1/L2 invalidate
    }
    __syncthreads();
  }
}

// ---------------------------------------------------------------------------
// entmax15 over rows of 128 (in-place on f32 scores). 1 wave per row.
// ---------------------------------------------------------------------------
__global__ __launch_bounds__(64) void k_entmax(float* __restrict__ p){
  long row = blockIdx.x;
  float* base = p + row*128;
  __shared__ float xo[128], xs[128], c1[128], c2[128];
  int t = threadIdx.x;
  float a = base[t]*0.5f, b = base[t+64]*0.5f;
  float m = wredmax(fmaxf(a,b));
  a -= m; b -= m;
  xo[t]=a; xo[t+64]=b; xs[t]=a; xs[t+64]=b;
  __syncthreads();
  for (int k2=2;k2<=128;k2<<=1){
    for (int j=k2>>1;j>0;j>>=1){
      int i = ((t & ~(j-1))<<1) | (t & (j-1));
      int ixj = i | j;
      float vi = xs[i], vj = xs[ixj];
      bool blk = (i & k2)==0;
      bool sw = blk ? (vi < vj) : (vi > vj);
      __syncthreads();
      if (sw){ xs[i]=vj; xs[ixj]=vi; }
      __syncthreads();
    }
  }
  c1[t]=xs[t];       c2[t]=xs[t]*xs[t];
  c1[t+64]=xs[t+64]; c2[t+64]=xs[t+64]*xs[t+64];
  __syncthreads();
  for (int d=1; d<128; d<<=1){
    float a1 = (t>=d)     ? c1[t-d]    : 0.f;
    float a2 = (t>=d)     ? c2[t-d]    : 0.f;
    float b1 = (t+64>=d)  ? c1[t+64-d] : 0.f;
    float b2 = (t+64>=d)  ? c2[t+64-d] : 0.f;
    float x1=c1[t], y1=c2[t], x2=c1[t+64], y2=c2[t+64];
    __syncthreads();
    c1[t]=x1+a1; c2[t]=y1+a2; c1[t+64]=x2+b1; c2[t+64]=y2+b2;
    __syncthreads();
  }
  float tau_a, tau_b; int cnt=0;
  {
    float rho = (float)(t+1);
    float mean = c1[t]/rho, msq = c2[t]/rho;
    float ss = rho*(msq-mean*mean);
    float delta = (1.f-ss)/rho;
    tau_a = mean - sqrtf(fmaxf(delta,0.f));
    cnt += (tau_a <= xs[t]) ? 1 : 0;
  }
  {
    float rho = (float)(t+65);
    float mean = c1[t+64]/rho, msq = c2[t+64]/rho;
    float ss = rho*(msq-mean*mean);
    float delta = (1.f-ss)/rho;
    tau_b = mean - sqrtf(fmaxf(delta,0.f));
    cnt += (tau_b <= xs[t+64]) ? 1 : 0;
  }
  __syncthreads();
  c1[t]=tau_a; c1[t+64]=tau_b;
  __syncthreads();
  int support = wredsumi(cnt);
  support = (support<1) ? 1 : ((support>128) ? 128 : support);
  float tau_star = c1[support-1];
  float oa = fmaxf(xo[t]-tau_star, 0.f);
  float ob = fmaxf(xo[t+64]-tau_star, 0.f);
  base[t] = oa*oa; base[t+64] = ob*ob;
}

// ---------------------------------------------------------------------------
__global__ void k_adjsem(const float* __restrict__ p, const int* __restrict__ nonpad,
                         ushort_t* __restrict__ adj_sem){
  int idx = blockIdx.x*blockDim.x + threadIdx.x;
  if (idx >= 128*128*128) return;
  int b = idx>>14, rem = idx&16383, i = rem>>7, j = rem&127;
  float s = 0.f;
  for (int h=0;h<6;h++) s += p[(long)b*98304 + h*16384 + i*128 + j];
  float v = s/6.0f;
  if (i==j) v = 1.0f;
  if (!nonpad[b*128+i]) v = 0.f;
  adj_sem[idx] = f2bf(v);
}

__global__ __launch_bounds__(64) void k_dn(const ushort_t* __restrict__ src, float* __restrict__ dnv){
  long row = blockIdx.x;
  int l = threadIdx.x;
  float s = bf2f(src[row*128+l]) + bf2f(src[row*128+l+64]);
  s = wredsum(s);
  if (l==0) dnv[row] = 1.0f/sqrtf(s+1.0f);
}

__global__ __launch_bounds__(64) void k_mean(const ushort_t* __restrict__ X, float* __restrict__ ymean){
  long row = blockIdx.x;
  float s=0.f;
  for (int d=threadIdx.x; d<600; d+=64) s += bf2f(X[row*600+d]);
  s = wredsum(s);
  if (threadIdx.x==0) ymean[row] = s/600.0f;
}

__global__ void k_senet(const float* __restrict__ ymean,
                        const ushort_t* __restrict__ w1, const ushort_t* __restrict__ b1,
                        const ushort_t* __restrict__ w2, const ushort_t* __restrict__ b2,
                        const int* __restrict__ nonpad, float* __restrict__ ysoft){
  int b = blockIdx.x, t = threadIdx.x;
  __shared__ float yv[128], z1[12], red[128];
  yv[t] = ymean[b*128+t];
  __syncthreads();
  if (t<12){
    float s = bf2f(b1[t]);
    for (int k2=0;k2<128;k2++) s += yv[k2]*bf2f(w1[t*128+k2]);
    z1[t] = fmaxf(s,0.f);
  }
  __syncthreads();
  float v = bf2f(b2[t]);
  for (int r=0;r<12;r++) v += z1[r]*bf2f(w2[t*12+r]);
  if (!nonpad[b*128+t]) v += NEGV;
  red[t]=v; __syncthreads();
  for (int s2=64;s2>0;s2>>=1){ if (t<s2) red[t]=fmaxf(red[t],red[t+s2]); __syncthreads(); }
  float mx = red[0]; __syncthreads();
  float e = expf(v-mx);
  red[t]=e; __syncthreads();
  for (int s2=64;s2>0;s2>>=1){ if (t<s2) red[t]+=red[t+s2]; __syncthreads(); }
  float sm = red[0];
  ysoft[b*128+t] = e/sm;
}

__global__ void k_scale2(const ushort_t* __restrict__ X, const float* __restrict__ ysoft,
                         const float* __restrict__ dnv, ushort_t* __restrict__ out){
  int i = blockIdx.x*blockDim.x + threadIdx.x;
  if (i >= 128*128*600) return;
  int row = i/600;
  out[i] = f2bf(bf2f(X[i])*ysoft[row]*dnv[row]);
}

__global__ void k_gather(const ushort_t* __restrict__ X, const int* __restrict__ left_len,
                         ushort_t* __restrict__ dst){
  int b = blockIdx.x;
  int lb = left_len[b];
  for (int d=threadIdx.x; d<600; d+=128)
    dst[b*600+d] = X[(long)(b*128+lb)*600+d];
}

__global__ __launch_bounds__(256) void k_pool(const ushort_t* __restrict__ g,
                                              const ushort_t* __restrict__ X,
                                              float* __restrict__ pooled, int poff){
  int b = blockIdx.x, tid = threadIdx.x;
  __shared__ float gs[600], sbuf[128], red[256];
  for (int d=tid; d<600; d+=256) gs[d] = bf2f(g[b*600+d]);
  __syncthreads();
  int wv = tid>>6, lane = tid&63;
  for (int jj=wv; jj<128; jj+=4){
    float s=0.f;
    for (int d=lane; d<600; d+=64) s += gs[d]*bf2f(X[(long)(b*128+jj)*600+d]);
    s = wredsum(s);
    if (lane==0) sbuf[jj]=s;
  }
  __syncthreads();
  float v = (tid<128) ? sbuf[tid] : -3.4e38f;
  red[tid]=v; __syncthreads();
  for (int s2=128;s2>0;s2>>=1){ if (tid<s2) red[tid]=fmaxf(red[tid],red[tid+s2]); __syncthreads(); }
  float mx = red[0]; __syncthreads();
  float e = (tid<128) ? expf(v-mx) : 0.f;
  red[tid]=e; __syncthreads();
  for (int s2=128;s2>0;s2>>=1){ if (tid<s2) red[tid]+=red[tid+s2]; __syncthreads(); }
  float sm = red[0]; __syncthreads();
  if (tid<128) sbuf[tid] = e/sm;
  __syncthreads();
  for (int d=tid; d<600; d+=256){
    float acc=0.f;
    for (int j=0;j<128;j++) acc += sbuf[j]*bf2f(X[(long)(b*128+j)*600+d]);
    pooled[(long)b*1200 + poff + d] = acc;
  }
}

__global__ __launch_bounds__(64) void k_final(const float* __restrict__ pooled,
                                              const ushort_t* __restrict__ fcw,
                                              const ushort_t* __restrict__ fcb,
                                              void* __restrict__ out,
                                              const ushort_t* __restrict__ probe_src){
  bool isbf = probe_is_bf16(probe_src);
  int b = blockIdx.x, lane = threadIdx.x;
  for (int p=0;p<3;p++){
    float s=0.f;
    for (int d=lane; d<1200; d+=64) s += pooled[(long)b*1200+d]*bf2f(fcw[d*3+p]);
    s = wredsum(s);
    if (lane==0){
      float r = s + bf2f(fcb[p]);
      if (isbf) ((ushort_t*)out)[b*3+p] = f2bf(r);
      else      ((float*)out)[b*3+p] = r;
    }
  }
}

// ---------------------------------------------------------------------------
extern "C" void kernel_launch(void* const* d_in, const int* in_sizes, int n_in,
                              void* d_out, int out_size, void* d_ws, size_t ws_size,
                              hipStream_t stream) {
  const int*      ti   = (const int*)d_in[0];
  const int*      ai   = (const int*)d_in[1];
  const int*      li   = (const int*)d_in[2];
  const int*      pi   = (const int*)d_in[3];
  const int*      aps  = (const int*)d_in[4];
  const ushort_t* probe = (const ushort_t*)d_in[7];

  char* w = (char*)d_ws; size_t off = 0;
  auto alloc = [&](size_t bytes)->char*{ char* p = w+off; off = (off+bytes+255)&~(size_t)255; return p; };

  int*   text_len = (int*)alloc(512);
  int*   left_len = (int*)alloc(512);
  int*   nonpad   = (int*)alloc(65536);
  float* asp_mean = (float*)alloc(153600);
  float* dn1      = (float*)alloc(65536);
  float* dn2      = (float*)alloc(65536);
  float* ymean    = (float*)alloc(65536);
  float* ysoft    = (float*)alloc(65536);
  ushort_t* wihpf = (ushort_t*)alloc(806400);
  ushort_t* wihpb = (ushort_t*)alloc(806400);
  ushort_t* whh2f = (ushort_t*)alloc(819200);   // [1280][320] row=j*4+gate
  ushort_t* whh2b = (ushort_t*)alloc(819200);
  ushort_t* hbuf  = (ushort_t*)alloc(327680);   // [2 dir][2 buf][128][320]
  int*      barr  = (int*)alloc(2048);          // [4][128]
  float* biasgf   = (float*)alloc(4800);
  float* biasgb   = (float*)alloc(4800);
  float* bqf      = (float*)alloc(2400);
  float* bkf      = (float*)alloc(2400);
  float* gc1bf    = (float*)alloc(2400);
  float* gc2bf    = (float*)alloc(2400);
  ushort_t* g1    = (ushort_t*)alloc(153600);
  ushort_t* g2    = (ushort_t*)alloc(153600);
  ushort_t* xr    = (ushort_t*)alloc(153600);
  ushort_t* xsr   = (ushort_t*)alloc(153600);
  float* pooled   = (float*)alloc(614400);
  ushort_t* adj_c  = (ushort_t*)alloc(4194304);
  ushort_t* pe_c   = (ushort_t*)alloc(2048);
  ushort_t* wihf_c = (ushort_t*)alloc(792000);
  ushort_t* wihb_c = (ushort_t*)alloc(792000);
  ushort_t* whhf_c = (ushort_t*)alloc(720000);
  ushort_t* whhb_c = (ushort_t*)alloc(720000);
  ushort_t* bihf_c = (ushort_t*)alloc(2400);
  ushort_t* bhhf_c = (ushort_t*)alloc(2400);
  ushort_t* bihb_c = (ushort_t*)alloc(2400);
  ushort_t* bhhb_c = (ushort_t*)alloc(2400);
  ushort_t* wq_c   = (ushort_t*)alloc(720000);
  ushort_t* bq_c   = (ushort_t*)alloc(1200);
  ushort_t* wk_c   = (ushort_t*)alloc(720000);
  ushort_t* bk_c   = (ushort_t*)alloc(1200);
  ushort_t* sw1_c  = (ushort_t*)alloc(3072);
  ushort_t* sb1_c  = (ushort_t*)alloc(256);
  ushort_t* sw2_c  = (ushort_t*)alloc(3072);
  ushort_t* sb2_c  = (ushort_t*)alloc(256);
  ushort_t* g1w_c  = (ushort_t*)alloc(720000);
  ushort_t* g1b_c  = (ushort_t*)alloc(1200);
  ushort_t* g2w_c  = (ushort_t*)alloc(720000);
  ushort_t* g2b_c  = (ushort_t*)alloc(1200);
  ushort_t* af1_c  = (ushort_t*)alloc(720000);
  ushort_t* af2_c  = (ushort_t*)alloc(720000);
  ushort_t* fcw_c  = (ushort_t*)alloc(7200);
  ushort_t* fcb_c  = (ushort_t*)alloc(256);
  ushort_t* embs  = (ushort_t*)alloc(11010048);
  ushort_t* textout = (ushort_t*)alloc(19660800);
  char* R = alloc(95420416);
  ushort_t* em_c    = (ushort_t*)(R);            // 18 MB; dead after k_embs
  ushort_t* gip_f   = (ushort_t*)(R);            // 41.9 MB [128t][320jj][128b][4g]
  ushort_t* gip_b   = (ushort_t*)(R+41943040);   // 41.9 MB; both dead after lstm2
  ushort_t* qh      = (ushort_t*)(R);
  ushort_t* kh      = (ushort_t*)(R+20447232);
  float*    scores  = (float*)(R+40894464);
  ushort_t* adj_sem = (ushort_t*)(R+91226112);
  ushort_t* se_x    = (ushort_t*)(R+40894464);
  ushort_t* Zb      = (ushort_t*)(R+60555264);
  ushort_t* x_sem   = (ushort_t*)(R);
  ushort_t* xb      = (ushort_t*)(R+20447232);
  (void)ws_size; (void)n_in; (void)in_sizes; (void)out_size;

  // --- normalize all float inputs to bf16 (cheap per-block probe, x8 vec) ---
  {
    const int idx[27] = {7,6, 8,9,13,10,14,11,12,15,16,17,18,19,20,21,22,23,24,25,26,27,28,29,30,31,32};
    ushort_t* dl[27] = {em_c,adj_c, pe_c,wihf_c,wihb_c,whhf_c,whhb_c,bihf_c,bhhf_c,bihb_c,bhhb_c,
                        wq_c,bq_c,wk_c,bk_c,sw1_c,sb1_c,sw2_c,sb2_c,
                        g1w_c,g1b_c,g2w_c,g2b_c,af1_c,af2_c,fcw_c,fcb_c};
    const long nl[27] = {9000000L,2097152L, 900,396000,396000,360000,360000,1200,1200,1200,1200,
                         360000,600,360000,600,1536,12,1536,128,
                         360000,600,360000,600,360000,360000,3600,3};
    for (int i=0;i<27;i++){
      long nb = ((nl[i]+7)/8 + 255)/256;
      k_cvt8<<<(int)nb,256,0,stream>>>(d_in[idx[i]], dl[i], nl[i], probe);
    }
  }

  // --- prep ---
  k_lens<<<128,128,0,stream>>>(ti, li, nonpad, text_len, left_len);
  k_aspmean<<<128,128,0,stream>>>(ai, em_c, asp_mean);
  k_embs<<<16384,128,0,stream>>>(ti, pi, aps, em_c, pe_c, asp_mean, embs);
  k_padcopy<<<(1200*336+255)/256,256,0,stream>>>(wihf_c, wihpf, 1200, 330, 336);
  k_padcopy<<<(1200*336+255)/256,256,0,stream>>>(wihb_c, wihpb, 1200, 330, 336);
  k_padwhh2<<<(1280*320+255)/256,256,0,stream>>>(whhf_c, whh2f);
  k_padwhh2<<<(1280*320+255)/256,256,0,stream>>>(whhb_c, whh2b);
  k_biassum<<<(1200+255)/256,256,0,stream>>>(bihf_c, bhhf_c, biasgf, 1200);
  k_biassum<<<(1200+255)/256,256,0,stream>>>(bihb_c, bhhb_c, biasgb, 1200);
  k_biascvt<<<3,256,0,stream>>>(bq_c, bqf, 600);
  k_biascvt<<<3,256,0,stream>>>(bk_c, bkf, 600);
  k_biascvt<<<3,256,0,stream>>>(g1b_c, gc1bf, 600);
  k_biascvt<<<3,256,0,stream>>>(g2b_c, gc2bf, 600);

  // --- input projections (embs @ Wih^T + bias), gate-packed for lstm2 ---
  gemm_k<1,4><<<dim3(128,10,1),256,0,stream>>>(16384,1200,336, embs,336,0, wihpf,336,0,
        nullptr, gip_f,0,0, biasgf,0,nullptr,nullptr);
  gemm_k<1,4><<<dim3(128,10,1),256,0,stream>>>(16384,1200,336, embs,336,0, wihpb,336,0,
        nullptr, gip_b,0,0, biasgb,0,nullptr,nullptr);

  // --- BiLSTM: register-resident Whh, 40 blocks, per-group L3 barrier ---
  hipMemsetAsync(hbuf, 0, 327680, stream);
  hipMemsetAsync(barr, 0, 2048, stream);
  lstm2_k<<<40,256,0,stream>>>(whh2f, whh2b, gip_f, gip_b, hbuf, barr, textout, text_len);

  // --- q/k projections, head-scattered (dk padded 100->104) ---
  hipMemsetAsync(qh, 0, 20447232, stream);
  hipMemsetAsync(kh, 0, 20447232, stream);
  gemm_k<1,2><<<dim3(128,5,1),256,0,stream>>>(16384,600,600, textout,600,0, wq_c,600,0,
        nullptr, qh,0,0, bqf,0,nullptr,nullptr);
  gemm_k<1,2><<<dim3(128,5,1),256,0,stream>>>(16384,600,600, textout,600,0, wk_c,600,0,
        nullptr, kh,0,0, bkf,0,nullptr,nullptr);

  // --- attention scores + mask ---
  gemm_k<1,3><<<dim3(1,1,768),256,0,stream>>>(128,128,104, qh,104,13312, kh,104,13312,
        scores, nullptr, 128, 16384, nullptr,0,nullptr, nonpad);

  // --- entmax15 (in place) ---
  k_entmax<<<98304,64,0,stream>>>(scores);

  // --- adjacency: head-mean + eye + valid; degree norms ---
  k_adjsem<<<(2097152+255)/256,256,0,stream>>>(scores, nonpad, adj_sem);
  k_dn<<<16384,64,0,stream>>>(adj_sem, dn1);
  k_dn<<<16384,64,0,stream>>>(adj_c, dn2);

  // --- SE #1 + GCN #1 (norm folded: Z = D (A (D * se * X))) ---
  k_mean<<<16384,64,0,stream>>>(textout, ymean);
  k_senet<<<128,128,0,stream>>>(ymean, sw1_c,sb1_c,sw2_c,sb2_c, nonpad, ysoft);
  k_scale2<<<(9830400+255)/256,256,0,stream>>>(textout, ysoft, dn1, se_x);
  gemm_k<0,1><<<dim3(1,5,128),256,0,stream>>>(128,600,128, adj_sem,128,16384, se_x,600,76800,
        nullptr, Zb,600,76800, nullptr,0, dn1, nullptr);
  gemm_k<0,1><<<dim3(128,5,1),256,0,stream>>>(16384,600,600, Zb,600,0, g1w_c,600,0,
        nullptr, x_sem,600,0, gc1bf,1,nullptr,nullptr);

  // --- SE #2 + GCN #2 (uses input adj) ---
  k_mean<<<16384,64,0,stream>>>(x_sem, ymean);
  k_senet<<<128,128,0,stream>>>(ymean, sw1_c,sb1_c,sw2_c,sb2_c, nonpad, ysoft);
  k_scale2<<<(9830400+255)/256,256,0,stream>>>(x_sem, ysoft, dn2, se_x);
  gemm_k<0,1><<<dim3(1,5,128),256,0,stream>>>(128,600,128, adj_c,128,16384, se_x,600,76800,
        nullptr, Zb,600,76800, nullptr,0, dn2, nullptr);
  gemm_k<0,1><<<dim3(128,5,1),256,0,stream>>>(16384,600,600, Zb,600,0, g2w_c,600,0,
        nullptr, xb,600,0, gc2bf,1,nullptr,nullptr);

  // --- biaffine pooling (only row left_len[b] of A1/A2 is ever used) ---
  k_gather<<<128,128,0,stream>>>(xb, left_len, xr);
  k_gather<<<128,128,0,stream>>>(x_sem, left_len, xsr);
  gemm_k<0,1><<<dim3(1,5,1),256,0,stream>>>(128,600,600, xr,600,0, af1_c,600,0,
        nullptr, g1,600,0, nullptr,0,nullptr,nullptr);
  gemm_k<0,1><<<dim3(1,5,1),256,0,stream>>>(128,600,600, xsr,600,0, af2_c,600,0,
        nullptr, g2,600,0, nullptr,0,nullptr,nullptr);
  k_pool<<<128,256,0,stream>>>(g1, x_sem, pooled, 0);
  k_pool<<<128,256,0,stream>>>(g2, xb, pooled, 600);

  // --- final FC (dtype-adaptive output) ---
  k_final<<<128,64,0,stream>>>(pooled, fcw_c, fcb_c, d_out, probe);
}

// Round 2
// 2273.619 us; speedup vs baseline: 1.6746x; 1.2205x over previous
//
#include <hip/hip_runtime.h>

typedef unsigned short ushort_t;
typedef unsigned int   uint_t;
typedef __attribute__((ext_vector_type(8))) short short8;
typedef __attribute__((ext_vector_type(4))) float floatx4;

#define NEGV -1000000000.0f

__device__ __forceinline__ float bf2f(ushort_t h){ return __uint_as_float(((uint_t)h)<<16); }
__device__ __forceinline__ ushort_t f2bf(float f){
  uint_t u = __float_as_uint(f);
  uint_t r = u + 0x7fffu + ((u>>16)&1u);
  return (ushort_t)(r>>16);
}
__device__ __forceinline__ float wredsum(float v){ for(int o=32;o;o>>=1) v += __shfl_xor(v,o); return v; }
__device__ __forceinline__ float wredmax(float v){ for(int o=32;o;o>>=1) v = fmaxf(v,__shfl_xor(v,o)); return v; }
__device__ __forceinline__ int   wredsumi(int v){ for(int o=32;o;o>>=1) v += __shfl_xor(v,o); return v; }

// coherent (cross-XCD) 16B load: bypasses L1/L2 via sc0 sc1 -> reads L3/IF.
template<int OFF>
__device__ __forceinline__ short8 ldg_b128_cohr(const ushort_t* p){
  short8 r;
  asm volatile("global_load_dwordx4 %0, %1, off offset:%2 sc0 sc1"
               : "=&v"(r) : "v"(p), "n"(OFF) : "memory");
  return r;
}
#define LD10C(dst, p) \
  dst[0]=ldg_b128_cohr<0>(p);   dst[1]=ldg_b128_cohr<64>(p);  \
  dst[2]=ldg_b128_cohr<128>(p); dst[3]=ldg_b128_cohr<192>(p); \
  dst[4]=ldg_b128_cohr<256>(p); dst[5]=ldg_b128_cohr<320>(p); \
  dst[6]=ldg_b128_cohr<384>(p); dst[7]=ldg_b128_cohr<448>(p); \
  dst[8]=ldg_b128_cohr<512>(p); dst[9]=ldg_b128_cohr<576>(p);

// coherent 2B store: write-through past the XCD L2 (sc0 sc1).
__device__ __forceinline__ void stg_b16_cohr(ushort_t* p, ushort_t v){
  uint_t u = v;
  asm volatile("global_store_short %0, %1, off sc0 sc1" :: "v"(p), "v"(u) : "memory");
}

// ---------------------------------------------------------------------------
// dtype-adaptive conversion, vectorized x8. Probe once per block in wave 0.
// ---------------------------------------------------------------------------
__global__ void k_cvt8(const void* __restrict__ src, ushort_t* __restrict__ dst,
                       long n, const ushort_t* __restrict__ probe_src){
  __shared__ int sflag;
  if (threadIdx.x < 64){
    ushort_t u = probe_src[2*threadIdx.x];
    int e = (u>>7)&0xFF;
    int c = (e>=100 && e<=140) ? 1 : 0;
    c = wredsumi(c);
    if (threadIdx.x==0) sflag = (c>32) ? 1 : 0;
  }
  __syncthreads();
  bool isbf = (sflag!=0);
  long base = (blockIdx.x*256L + threadIdx.x)*8;
  if (base>=n) return;
  if (isbf){
    if (base+8<=n) *(uint4*)(dst+base) = *(const uint4*)((const ushort_t*)src+base);
    else for (long i=base;i<n;i++) dst[i]=((const ushort_t*)src)[i];
  } else {
    const float* s = (const float*)src;
    if (base+8<=n){
      float4 v0 = *(const float4*)(s+base);
      float4 v1 = *(const float4*)(s+base+4);
      ushort_t o[8] = {f2bf(v0.x),f2bf(v0.y),f2bf(v0.z),f2bf(v0.w),
                       f2bf(v1.x),f2bf(v1.y),f2bf(v1.z),f2bf(v1.w)};
      *(uint4*)(dst+base) = *(uint4*)o;
    } else {
      for (long i=base;i<n;i++) dst[i]=f2bf(s[i]);
    }
  }
}

__device__ __forceinline__ bool probe_is_bf16(const ushort_t* probe_src){
  int c=0;
  #pragma unroll 1
  for (int i=0;i<64;i++){
    ushort_t u = probe_src[2*i];
    int e = (u>>7)&0xFF;
    c += (e>=100 && e<=140) ? 1 : 0;
  }
  return c>32;
}

// ---------------------------------------------------------------------------
// small prep kernels
// ---------------------------------------------------------------------------
__global__ void k_lens(const int* __restrict__ ti, const int* __restrict__ li,
                       int* __restrict__ nonpad, int* __restrict__ text_len,
                       int* __restrict__ left_len){
  int b = blockIdx.x, t = threadIdx.x;
  nonpad[b*128+t] = (ti[b*128+t]!=0) ? 1 : 0;
  if (t==0){
    int c=0; for (int k2=0;k2<128;k2++) c += (ti[b*128+k2]!=0);
    text_len[b]=c;
    int l=0; for (int k2=0;k2<24;k2++) l += (li[b*24+k2]!=0);
    left_len[b]=l;
  }
}

__global__ void k_aspmean(const int* __restrict__ ai, const ushort_t* __restrict__ em,
                          float* __restrict__ asp_mean){
  int b = blockIdx.x;
  int idxs[5]; int cnt=0;
  for (int a=0;a<5;a++){ int ix=ai[b*5+a]; idxs[a]=ix; cnt += (ix!=0); }
  float inv = 1.0f/(float)cnt;
  for (int d=threadIdx.x; d<300; d+=128){
    float s=0.f;
    for (int a=0;a<5;a++) if (idxs[a]) s += bf2f(em[(long)idxs[a]*300+d]);
    asp_mean[b*300+d] = s*inv;
  }
}

__global__ void k_embs(const int* __restrict__ ti, const int* __restrict__ pi,
                       const int* __restrict__ asp_post,
                       const ushort_t* __restrict__ em, const ushort_t* __restrict__ pe,
                       const float* __restrict__ asp_mean, ushort_t* __restrict__ embs){
  int blk = blockIdx.x;
  int b = blk>>7, t = blk&127;
  int ap = asp_post[b];
  int tix = ti[b*128+t];
  int pix = pi[b*128+t];
  for (int col=threadIdx.x; col<336; col+=128){
    ushort_t v;
    if (col<300) v = (t==ap) ? f2bf(asp_mean[b*300+col]) : em[(long)tix*300+col];
    else if (col<330) v = pe[pix*30 + (col-300)];
    else v = 0;
    embs[(long)(b*128+t)*336 + col] = v;
  }
}

// Wih repack for gate-packed gi: dst[1280][336], row' = j*4+gate
// (j padded 300->320, K 330->336). src row = gate*300+j, 330 cols.
__global__ void k_padwih2(const ushort_t* __restrict__ src, ushort_t* __restrict__ dst){
  int i = blockIdx.x*blockDim.x + threadIdx.x;
  if (i >= 1280*336) return;
  int r = i/336, k = i - r*336;
  int j = r>>2, gate = r&3;
  ushort_t v = 0;
  if (j<300 && k<330) v = src[(long)(gate*300+j)*330 + k];
  dst[i] = v;
}

// Whh repack for reg-resident LSTM: dst[1280][320] bf16, row' = j*4 + gate
// (j padded 300->320, K 300->320, zeros elsewhere). src row = gate*300 + j.
__global__ void k_padwhh2(const ushort_t* __restrict__ src, ushort_t* __restrict__ dst){
  int i = blockIdx.x*blockDim.x + threadIdx.x;
  if (i >= 1280*320) return;
  int r = i/320, k = i - r*320;
  int j = r>>2, gate = r&3;
  ushort_t v = 0;
  if (j<300 && k<300) v = src[(long)(gate*300+j)*300 + k];
  dst[i] = v;
}

// gate-packed bias: dst[j*4+gate] = bih[gate*300+j] + bhh[gate*300+j]
__global__ void k_biassum2(const ushort_t* __restrict__ a, const ushort_t* __restrict__ b,
                           float* __restrict__ dst){
  int i = blockIdx.x*blockDim.x + threadIdx.x;
  if (i>=1280) return;
  int j = i>>2, g = i&3;
  dst[i] = (j<300) ? (bf2f(a[g*300+j]) + bf2f(b[g*300+j])) : 0.f;
}

__global__ void k_biascvt(const ushort_t* __restrict__ a, float* __restrict__ dst, int n){
  int i = blockIdx.x*blockDim.x + threadIdx.x;
  if (i<n) dst[i] = bf2f(a[i]);
}

// ---------------------------------------------------------------------------
// generic bf16 MFMA GEMM: 128x128 tile, 4 waves (2x2), each 64x64 via 4x4
// frags of 16x16x32.  TB=1: C = A * B^T.  TB=0: C = A * B.
// MODE 1: bf16 store (opt bias/relu/rowscale)
// MODE 2: qk head-scatter bf16 store (bias), T=128, dk=100->104
// MODE 3: f32 store, *0.1 and nonpad column mask (attention scores)
// ---------------------------------------------------------------------------
template<int TB, int MODE>
__global__ __launch_bounds__(256) void gemm_k(
    int M, int N, int K,
    const ushort_t* __restrict__ A, long lda, long sAz,
    const ushort_t* __restrict__ B, long ldb, long sBz,
    float* __restrict__ Cf, ushort_t* __restrict__ Cb, long ldc, long sCz,
    const float* __restrict__ bias, int relu,
    const float* __restrict__ rowscale,
    const int* __restrict__ nonpad)
{
  __shared__ ushort_t As[128*40];
  __shared__ ushort_t Bs[128*40];
  const int tid = threadIdx.x;
  const int m0 = blockIdx.x*128, n0 = blockIdx.y*128;
  const int z = blockIdx.z;
  const ushort_t* Ap = A + (long)z*sAz;
  const ushort_t* Bp = B + (long)z*sBz;
  floatx4 acc[4][4];
  #pragma unroll
  for (int i=0;i<4;i++)
    #pragma unroll
    for (int j=0;j<4;j++){ acc[i][j][0]=0.f; acc[i][j][1]=0.f; acc[i][j][2]=0.f; acc[i][j][3]=0.f; }
  const int w = tid>>6, wm = w&1, wn = w>>1;
  const int lane = tid&63, lr = lane&15, lq = lane>>4;

  for (int k0=0;k0<K;k0+=32){
    #pragma unroll
    for (int c2=0;c2<2;c2++){
      int ch = tid + 256*c2;
      int row = ch>>2, kc = (ch&3)*8;
      int gr = m0+row, gk = k0+kc;
      uint4 v{};
      if (gr<M && gk<K) v = *(const uint4*)(Ap + (long)gr*lda + gk);
      *(uint4*)(&As[row*40+kc]) = v;
    }
    if (TB){
      #pragma unroll
      for (int c2=0;c2<2;c2++){
        int ch = tid + 256*c2;
        int row = ch>>2, kc = (ch&3)*8;
        int gn = n0+row, gk = k0+kc;
        uint4 v{};
        if (gn<N && gk<K) v = *(const uint4*)(Bp + (long)gn*ldb + gk);
        int sw = kc ^ (((row>>3)&3)<<3);
        *(uint4*)(&Bs[row*40+sw]) = v;
      }
    } else {
      #pragma unroll
      for (int c2=0;c2<2;c2++){
        int ch = tid + 256*c2;
        int kk = ch>>4, nc = (ch&15)*8;
        int gk = k0+kk, gn = n0+nc;
        uint4 v{};
        if (gk<K && gn<N) v = *(const uint4*)(Bp + (long)gk*ldb + gn);
        uint_t wsv[4] = {v.x, v.y, v.z, v.w};
        #pragma unroll
        for (int e=0;e<8;e++){
          ushort_t hv = (e&1) ? (ushort_t)(wsv[e>>1]>>16) : (ushort_t)(wsv[e>>1]&0xffffu);
          int n = nc+e;
          int sw = kk ^ (((n>>3)&3)<<3);
          Bs[n*40+sw] = hv;
        }
      }
    }
    __syncthreads();
    short8 af[4], bfv[4];
    #pragma unroll
    for (int i=0;i<4;i++) af[i] = *(const short8*)(&As[(wm*64+i*16+lr)*40 + lq*8]);
    #pragma unroll
    for (int j=0;j<4;j++){
      int n = wn*64+j*16+lr;
      int sw = (lq*8) ^ (((n>>3)&3)<<3);
      bfv[j] = *(const short8*)(&Bs[n*40+sw]);
    }
    #pragma unroll
    for (int i=0;i<4;i++)
      #pragma unroll
      for (int j=0;j<4;j++)
        acc[i][j] = __builtin_amdgcn_mfma_f32_16x16x32_bf16(af[i], bfv[j], acc[i][j], 0,0,0);
    __syncthreads();
  }

  #pragma unroll
  for (int i=0;i<4;i++){
    #pragma unroll
    for (int j=0;j<4;j++){
      #pragma unroll
      for (int r=0;r<4;r++){
        int row = m0 + wm*64 + i*16 + lq*4 + r;
        int col = n0 + wn*64 + j*16 + lr;
        if (row<M && col<N){
          float v = acc[i][j][r];
          if (rowscale) v *= rowscale[(long)z*M + row];
          if (bias) v += bias[col];
          if (relu && v<0.f) v = 0.f;
          if (MODE==1){
            Cb[(long)z*sCz + (long)row*ldc + col] = f2bf(v);
          } else if (MODE==2){
            int b = row>>7, t = row&127;
            int h = col/100, d = col - h*100;
            Cb[ ((long)((b*6+h)*128+t))*104 + d ] = f2bf(v);
          } else if (MODE==3){
            v *= 0.1f;
            if (!nonpad[(z/6)*128 + col]) v = NEGV;
            Cf[(long)z*sCz + (long)row*ldc + col] = v;
          }
        }
      }
    }
  }
}

// ---------------------------------------------------------------------------
// Register-resident BiLSTM, fence-free cross-XCD h exchange.
// Grid: 40 blocks = 2 dirs x 10 j-slices(32 hidden each) x 2 batch-halves(64).
// Block: 256 threads = 4 waves (1/SIMD). Each wave holds its Whh slice
// (4 Mtiles x 10 kfrags = 160 regs) for ALL 128 steps: zero A-traffic.
// A rows packed j*4+gate -> each lane's floatx4 = 4 gate pre-activations of
// one (j,b); the cell update is lane-local; c,h persist in registers.
// h ping-pongs through a global buffer using sc0|sc1 (write-through /
// L2-bypass) accesses ONLY for h + barrier word -> no __threadfence, so no
// per-step buffer_wbl2 / buffer_inv (that was 22k cycles/step in round 1).
// Producer order: sc1 stores -> s_waitcnt vmcnt(0) -> barrier -> agent atomic.
// Consumer: spin on agent atomic (coherent) -> sc1 loads of h.
// gi comes gate-packed (Wih rows reordered j*4+gate): one 8B load/(j,b).
// ---------------------------------------------------------------------------
__global__ __launch_bounds__(256,1) void lstm2_k(
    const ushort_t* __restrict__ whh2f, const ushort_t* __restrict__ whh2b,
    const ushort_t* __restrict__ gipf, const ushort_t* __restrict__ gipb,
    ushort_t* __restrict__ hbuf,          // [2 dir][2 buf][128 b][320] bf16
    int* __restrict__ barr,               // [4 grp][128 step]
    ushort_t* __restrict__ text_out, const int* __restrict__ text_len)
{
  const int bx = blockIdx.x;
  const int slice = bx % 10;
  const int grp   = bx / 10;              // 0..3 = (bh<<1)|dir
  const int dir = grp & 1, bh = grp >> 1;
  const ushort_t* __restrict__ whh = dir ? whh2b : whh2f;
  const ushort_t* __restrict__ gip = dir ? gipb : gipf;
  ushort_t* hb = hbuf + (long)dir * (2L*128*320);
  int* bar = barr + grp*128;

  const int tid = threadIdx.x;
  const int w = tid>>6, lane = tid&63, lr = lane&15, lq = lane>>4;
  const int wm = w&1, wn = w>>1;          // wave grid: 2 Mgroups x 2 Ngroups

  // ---- Whh slice -> registers (once) ----
  short8 a[4][10];
  #pragma unroll
  for (int mi=0;mi<4;mi++){
    const ushort_t* ar = whh + (long)(slice*128 + (wm*4+mi)*16 + lr)*320 + lq*8;
    #pragma unroll
    for (int kf=0;kf<10;kf++) a[mi][kf] = *(const short8*)(ar + kf*32);
  }

  // ---- lane-owned (jj, b) pairs ----
  int jj_[4], b_[2], tl_[2];
  #pragma unroll
  for (int mi=0;mi<4;mi++) jj_[mi] = slice*32 + (wm*4+mi)*4 + lq;
  #pragma unroll
  for (int ni=0;ni<2;ni++){ b_[ni] = bh*64 + (wn*2+ni)*16 + lr; tl_[ni] = text_len[b_[ni]]; }

  float    c_st[4][2];
  ushort_t h_st[4][2];
  #pragma unroll
  for (int mi=0;mi<4;mi++){ c_st[mi][0]=0.f; c_st[mi][1]=0.f; h_st[mi][0]=0; h_st[mi][1]=0; }

  for (int s=0; s<128; s++){
    const int t = dir ? (127-s) : s;
    const ushort_t* rb = hb + (long)(s&1)*(128L*320);
    ushort_t*       wb = hb + (long)((s+1)&1)*(128L*320);

    // gi loads (plain; gi is read-only, L2-cacheable); 8B per (jj,b)
    uint2 gp[4][2];
    #pragma unroll
    for (int mi=0;mi<4;mi++)
      #pragma unroll
      for (int ni=0;ni<2;ni++)
        gp[mi][ni] = *(const uint2*)(gip + ((long)(b_[ni]*128 + t))*1280 + jj_[mi]*4);

    // h B-fragments: coherent loads (bypass stale L1/L2, read L3)
    short8 bfr[2][10];
    {
      const ushort_t* pa0 = rb + (long)b_[0]*320 + lq*8;
      const ushort_t* pa1 = rb + (long)b_[1]*320 + lq*8;
      LD10C(bfr[0], pa0);
      LD10C(bfr[1], pa1);
    }
    asm volatile("s_waitcnt vmcnt(0)" ::: "memory");
    __builtin_amdgcn_sched_barrier(0);

    floatx4 acc[4][2];
    #pragma unroll
    for (int mi=0;mi<4;mi++)
      #pragma unroll
      for (int ni=0;ni<2;ni++){ acc[mi][ni][0]=0.f; acc[mi][ni][1]=0.f; acc[mi][ni][2]=0.f; acc[mi][ni][3]=0.f; }

    #pragma unroll
    for (int kf=0;kf<10;kf++)
      #pragma unroll
      for (int mi=0;mi<4;mi++)
        #pragma unroll
        for (int ni=0;ni<2;ni++)
          acc[mi][ni] = __builtin_amdgcn_mfma_f32_16x16x32_bf16(a[mi][kf], bfr[ni][kf], acc[mi][ni], 0,0,0);

    // lane-local cell update
    #pragma unroll
    for (int mi=0;mi<4;mi++){
      #pragma unroll
      for (int ni=0;ni<2;ni++){
        float g_i = acc[mi][ni][0] + bf2f((ushort_t)(gp[mi][ni].x & 0xffffu));
        float g_f = acc[mi][ni][1] + bf2f((ushort_t)(gp[mi][ni].x >> 16));
        float g_g = acc[mi][ni][2] + bf2f((ushort_t)(gp[mi][ni].y & 0xffffu));
        float g_o = acc[mi][ni][3] + bf2f((ushort_t)(gp[mi][ni].y >> 16));
        float ig = 1.f/(1.f+expf(-g_i));
        float fg = 1.f/(1.f+expf(-g_f));
        float gg = tanhf(g_g);
        float og = 1.f/(1.f+expf(-g_o));
        float cn = fg*c_st[mi][ni] + ig*gg;
        float hn = og*tanhf(cn);
        bool m = (t < tl_[ni]);
        if (m) c_st[mi][ni] = cn;
        ushort_t hv = m ? f2bf(hn) : h_st[mi][ni];
        h_st[mi][ni] = hv;
        if (jj_[mi] < 300){
          stg_b16_cohr(wb + (long)b_[ni]*320 + jj_[mi], hv);
          text_out[((long)(b_[ni]*128 + t))*600 + dir*300 + jj_[mi]] = m ? f2bf(hn) : (ushort_t)0;
        }
      }
    }

    // drain stores (sc1 -> visible at coherent point once vmcnt==0)
    asm volatile("s_waitcnt vmcnt(0)" ::: "memory");
    __syncthreads();
    if (tid==0){
      __hip_atomic_fetch_add(&bar[s], 1, __ATOMIC_RELAXED, __HIP_MEMORY_SCOPE_AGENT);
      while (__hip_atomic_load(&bar[s], __ATOMIC_RELAXED, __HIP_MEMORY_SCOPE_AGENT) < 10)
        __builtin_amdgcn_s_sleep(1);
    }
    __syncthreads();
  }
}

// ---------------------------------------------------------------------------
// entmax15 over rows of 128 (in-place on f32 scores). 1 wave per row.
// ---------------------------------------------------------------------------
__global__ __launch_bounds__(64) void k_entmax(float* __restrict__ p){
  long row = blockIdx.x;
  float* base = p + row*128;
  __shared__ float xo[128], xs[128], c1[128], c2[128];
  int t = threadIdx.x;
  float a = base[t]*0.5f, b = base[t+64]*0.5f;
  float m = wredmax(fmaxf(a,b));
  a -= m; b -= m;
  xo[t]=a; xo[t+64]=b; xs[t]=a; xs[t+64]=b;
  __syncthreads();
  for (int k2=2;k2<=128;k2<<=1){
    for (int j=k2>>1;j>0;j>>=1){
      int i = ((t & ~(j-1))<<1) | (t & (j-1));
      int ixj = i | j;
      float vi = xs[i], vj = xs[ixj];
      bool blk = (i & k2)==0;
      bool sw = blk ? (vi < vj) : (vi > vj);
      __syncthreads();
      if (sw){ xs[i]=vj; xs[ixj]=vi; }
      __syncthreads();
    }
  }
  c1[t]=xs[t];       c2[t]=xs[t]*xs[t];
  c1[t+64]=xs[t+64]; c2[t+64]=xs[t+64]*xs[t+64];
  __syncthreads();
  for (int d=1; d<128; d<<=1){
    float a1 = (t>=d)     ? c1[t-d]    : 0.f;
    float a2 = (t>=d)     ? c2[t-d]    : 0.f;
    float b1 = (t+64>=d)  ? c1[t+64-d] : 0.f;
    float b2 = (t+64>=d)  ? c2[t+64-d] : 0.f;
    float x1=c1[t], y1=c2[t], x2=c1[t+64], y2=c2[t+64];
    __syncthreads();
    c1[t]=x1+a1; c2[t]=y1+a2; c1[t+64]=x2+b1; c2[t+64]=y2+b2;
    __syncthreads();
  }
  float tau_a, tau_b; int cnt=0;
  {
    float rho = (float)(t+1);
    float mean = c1[t]/rho, msq = c2[t]/rho;
    float ss = rho*(msq-mean*mean);
    float delta = (1.f-ss)/rho;
    tau_a = mean - sqrtf(fmaxf(delta,0.f));
    cnt += (tau_a <= xs[t]) ? 1 : 0;
  }
  {
    float rho = (float)(t+65);
    float mean = c1[t+64]/rho, msq = c2[t+64]/rho;
    float ss = rho*(msq-mean*mean);
    float delta = (1.f-ss)/rho;
    tau_b = mean - sqrtf(fmaxf(delta,0.f));
    cnt += (tau_b <= xs[t+64]) ? 1 : 0;
  }
  __syncthreads();
  c1[t]=tau_a; c1[t+64]=tau_b;
  __syncthreads();
  int support = wredsumi(cnt);
  support = (support<1) ? 1 : ((support>128) ? 128 : support);
  float tau_star = c1[support-1];
  float oa = fmaxf(xo[t]-tau_star, 0.f);
  float ob = fmaxf(xo[t+64]-tau_star, 0.f);
  base[t] = oa*oa; base[t+64] = ob*ob;
}

// ---------------------------------------------------------------------------
__global__ void k_adjsem(const float* __restrict__ p, const int* __restrict__ nonpad,
                         ushort_t* __restrict__ adj_sem){
  int idx = blockIdx.x*blockDim.x + threadIdx.x;
  if (idx >= 128*128*128) return;
  int b = idx>>14, rem = idx&16383, i = rem>>7, j = rem&127;
  float s = 0.f;
  for (int h=0;h<6;h++) s += p[(long)b*98304 + h*16384 + i*128 + j];
  float v = s/6.0f;
  if (i==j) v = 1.0f;
  if (!nonpad[b*128+i]) v = 0.f;
  adj_sem[idx] = f2bf(v);
}

__global__ __launch_bounds__(64) void k_dn(const ushort_t* __restrict__ src, float* __restrict__ dnv){
  long row = blockIdx.x;
  int l = threadIdx.x;
  float s = bf2f(src[row*128+l]) + bf2f(src[row*128+l+64]);
  s = wredsum(s);
  if (l==0) dnv[row] = 1.0f/sqrtf(s+1.0f);
}

__global__ __launch_bounds__(64) void k_mean(const ushort_t* __restrict__ X, float* __restrict__ ymean){
  long row = blockIdx.x;
  float s=0.f;
  for (int d=threadIdx.x; d<600; d+=64) s += bf2f(X[row*600+d]);
  s = wredsum(s);
  if (threadIdx.x==0) ymean[row] = s/600.0f;
}

__global__ void k_senet(const float* __restrict__ ymean,
                        const ushort_t* __restrict__ w1, const ushort_t* __restrict__ b1,
                        const ushort_t* __restrict__ w2, const ushort_t* __restrict__ b2,
                        const int* __restrict__ nonpad, float* __restrict__ ysoft){
  int b = blockIdx.x, t = threadIdx.x;
  __shared__ float yv[128], z1[12], red[128];
  yv[t] = ymean[b*128+t];
  __syncthreads();
  if (t<12){
    float s = bf2f(b1[t]);
    for (int k2=0;k2<128;k2++) s += yv[k2]*bf2f(w1[t*128+k2]);
    z1[t] = fmaxf(s,0.f);
  }
  __syncthreads();
  float v = bf2f(b2[t]);
  for (int r=0;r<12;r++) v += z1[r]*bf2f(w2[t*12+r]);
  if (!nonpad[b*128+t]) v += NEGV;
  red[t]=v; __syncthreads();
  for (int s2=64;s2>0;s2>>=1){ if (t<s2) red[t]=fmaxf(red[t],red[t+s2]); __syncthreads(); }
  float mx = red[0]; __syncthreads();
  float e = expf(v-mx);
  red[t]=e; __syncthreads();
  for (int s2=64;s2>0;s2>>=1){ if (t<s2) red[t]+=red[t+s2]; __syncthreads(); }
  float sm = red[0];
  ysoft[b*128+t] = e/sm;
}

__global__ void k_scale2(const ushort_t* __restrict__ X, const float* __restrict__ ysoft,
                         const float* __restrict__ dnv, ushort_t* __restrict__ out){
  int i = blockIdx.x*blockDim.x + threadIdx.x;
  if (i >= 128*128*600) return;
  int row = i/600;
  out[i] = f2bf(bf2f(X[i])*ysoft[row]*dnv[row]);
}

__global__ void k_gather(const ushort_t* __restrict__ X, const int* __restrict__ left_len,
                         ushort_t* __restrict__ dst){
  int b = blockIdx.x;
  int lb = left_len[b];
  for (int d=threadIdx.x; d<600; d+=128)
    dst[b*600+d] = X[(long)(b*128+lb)*600+d];
}

__global__ __launch_bounds__(256) void k_pool(const ushort_t* __restrict__ g,
                                              const ushort_t* __restrict__ X,
                                              float* __restrict__ pooled, int poff){
  int b = blockIdx.x, tid = threadIdx.x;
  __shared__ float gs[600], sbuf[128], red[256];
  for (int d=tid; d<600; d+=256) gs[d] = bf2f(g[b*600+d]);
  __syncthreads();
  int wv = tid>>6, lane = tid&63;
  for (int jj=wv; jj<128; jj+=4){
    float s=0.f;
    for (int d=lane; d<600; d+=64) s += gs[d]*bf2f(X[(long)(b*128+jj)*600+d]);
    s = wredsum(s);
    if (lane==0) sbuf[jj]=s;
  }
  __syncthreads();
  float v = (tid<128) ? sbuf[tid] : -3.4e38f;
  red[tid]=v; __syncthreads();
  for (int s2=128;s2>0;s2>>=1){ if (tid<s2) red[tid]=fmaxf(red[tid],red[tid+s2]); __syncthreads(); }
  float mx = red[0]; __syncthreads();
  float e = (tid<128) ? expf(v-mx) : 0.f;
  red[tid]=e; __syncthreads();
  for (int s2=128;s2>0;s2>>=1){ if (tid<s2) red[tid]+=red[tid+s2]; __syncthreads(); }
  float sm = red[0]; __syncthreads();
  if (tid<128) sbuf[tid] = e/sm;
  __syncthreads();
  for (int d=tid; d<600; d+=256){
    float acc=0.f;
    for (int j=0;j<128;j++) acc += sbuf[j]*bf2f(X[(long)(b*128+j)*600+d]);
    pooled[(long)b*1200 + poff + d] = acc;
  }
}

__global__ __launch_bounds__(64) void k_final(const float* __restrict__ pooled,
                                              const ushort_t* __restrict__ fcw,
                                              const ushort_t* __restrict__ fcb,
                                              void* __restrict__ out,
                                              const ushort_t* __restrict__ probe_src){
  bool isbf = probe_is_bf16(probe_src);
  int b = blockIdx.x, lane = threadIdx.x;
  for (int p=0;p<3;p++){
    float s=0.f;
    for (int d=lane; d<1200; d+=64) s += pooled[(long)b*1200+d]*bf2f(fcw[d*3+p]);
    s = wredsum(s);
    if (lane==0){
      float r = s + bf2f(fcb[p]);
      if (isbf) ((ushort_t*)out)[b*3+p] = f2bf(r);
      else      ((float*)out)[b*3+p] = r;
    }
  }
}

// ---------------------------------------------------------------------------
extern "C" void kernel_launch(void* const* d_in, const int* in_sizes, int n_in,
                              void* d_out, int out_size, void* d_ws, size_t ws_size,
                              hipStream_t stream) {
  const int*      ti   = (const int*)d_in[0];
  const int*      ai   = (const int*)d_in[1];
  const int*      li   = (const int*)d_in[2];
  const int*      pi   = (const int*)d_in[3];
  const int*      aps  = (const int*)d_in[4];
  const ushort_t* probe = (const ushort_t*)d_in[7];

  char* w = (char*)d_ws; size_t off = 0;
  auto alloc = [&](size_t bytes)->char*{ char* p = w+off; off = (off+bytes+255)&~(size_t)255; return p; };

  int*   text_len = (int*)alloc(512);
  int*   left_len = (int*)alloc(512);
  int*   nonpad   = (int*)alloc(65536);
  float* asp_mean = (float*)alloc(153600);
  float* dn1      = (float*)alloc(65536);
  float* dn2      = (float*)alloc(65536);
  float* ymean    = (float*)alloc(65536);
  float* ysoft    = (float*)alloc(65536);
  ushort_t* wihpf = (ushort_t*)alloc(860160);   // [1280][336] row=j*4+gate
  ushort_t* wihpb = (ushort_t*)alloc(860160);
  ushort_t* whh2f = (ushort_t*)alloc(819200);   // [1280][320] row=j*4+gate
  ushort_t* whh2b = (ushort_t*)alloc(819200);
  ushort_t* hbuf  = (ushort_t*)alloc(327680);   // [2 dir][2 buf][128][320]
  int*      barr  = (int*)alloc(2048);          // [4][128]
  float* biasgf   = (float*)alloc(5120);        // [1280] gate-packed
  float* biasgb   = (float*)alloc(5120);
  float* bqf      = (float*)alloc(2400);
  float* bkf      = (float*)alloc(2400);
  float* gc1bf    = (float*)alloc(2400);
  float* gc2bf    = (float*)alloc(2400);
  ushort_t* g1    = (ushort_t*)alloc(153600);
  ushort_t* g2    = (ushort_t*)alloc(153600);
  ushort_t* xr    = (ushort_t*)alloc(153600);
  ushort_t* xsr   = (ushort_t*)alloc(153600);
  float* pooled   = (float*)alloc(614400);
  ushort_t* adj_c  = (ushort_t*)alloc(4194304);
  ushort_t* pe_c   = (ushort_t*)alloc(2048);
  ushort_t* wihf_c = (ushort_t*)alloc(792000);
  ushort_t* wihb_c = (ushort_t*)alloc(792000);
  ushort_t* whhf_c = (ushort_t*)alloc(720000);
  ushort_t* whhb_c = (ushort_t*)alloc(720000);
  ushort_t* bihf_c = (ushort_t*)alloc(2400);
  ushort_t* bhhf_c = (ushort_t*)alloc(2400);
  ushort_t* bihb_c = (ushort_t*)alloc(2400);
  ushort_t* bhhb_c = (ushort_t*)alloc(2400);
  ushort_t* wq_c   = (ushort_t*)alloc(720000);
  ushort_t* bq_c   = (ushort_t*)alloc(1200);
  ushort_t* wk_c   = (ushort_t*)alloc(720000);
  ushort_t* bk_c   = (ushort_t*)alloc(1200);
  ushort_t* sw1_c  = (ushort_t*)alloc(3072);
  ushort_t* sb1_c  = (ushort_t*)alloc(256);
  ushort_t* sw2_c  = (ushort_t*)alloc(3072);
  ushort_t* sb2_c  = (ushort_t*)alloc(256);
  ushort_t* g1w_c  = (ushort_t*)alloc(720000);
  ushort_t* g1b_c  = (ushort_t*)alloc(1200);
  ushort_t* g2w_c  = (ushort_t*)alloc(720000);
  ushort_t* g2b_c  = (ushort_t*)alloc(1200);
  ushort_t* af1_c  = (ushort_t*)alloc(720000);
  ushort_t* af2_c  = (ushort_t*)alloc(720000);
  ushort_t* fcw_c  = (ushort_t*)alloc(7200);
  ushort_t* fcb_c  = (ushort_t*)alloc(256);
  ushort_t* embs  = (ushort_t*)alloc(11010048);
  ushort_t* textout = (ushort_t*)alloc(19660800);
  char* R = alloc(95420416);
  ushort_t* em_c    = (ushort_t*)(R);            // 18 MB; dead after k_embs
  ushort_t* gip_f   = (ushort_t*)(R);            // 41.9 MB [b,t][1280] gate-packed
  ushort_t* gip_b   = (ushort_t*)(R+41943040);   // 41.9 MB; both dead after lstm2
  ushort_t* qh      = (ushort_t*)(R);
  ushort_t* kh      = (ushort_t*)(R+20447232);
  float*    scores  = (float*)(R+40894464);
  ushort_t* adj_sem = (ushort_t*)(R+91226112);
  ushort_t* se_x    = (ushort_t*)(R+40894464);
  ushort_t* Zb      = (ushort_t*)(R+60555264);
  ushort_t* x_sem   = (ushort_t*)(R);
  ushort_t* xb      = (ushort_t*)(R+20447232);
  (void)ws_size; (void)n_in; (void)in_sizes; (void)out_size;

  // --- normalize all float inputs to bf16 (cheap per-block probe, x8 vec) ---
  {
    const int idx[27] = {7,6, 8,9,13,10,14,11,12,15,16,17,18,19,20,21,22,23,24,25,26,27,28,29,30,31,32};
    ushort_t* dl[27] = {em_c,adj_c, pe_c,wihf_c,wihb_c,whhf_c,whhb_c,bihf_c,bhhf_c,bihb_c,bhhb_c,
                        wq_c,bq_c,wk_c,bk_c,sw1_c,sb1_c,sw2_c,sb2_c,
                        g1w_c,g1b_c,g2w_c,g2b_c,af1_c,af2_c,fcw_c,fcb_c};
    const long nl[27] = {9000000L,2097152L, 900,396000,396000,360000,360000,1200,1200,1200,1200,
                         360000,600,360000,600,1536,12,1536,128,
                         360000,600,360000,600,360000,360000,3600,3};
    for (int i=0;i<27;i++){
      long nb = ((nl[i]+7)/8 + 255)/256;
      k_cvt8<<<(int)nb,256,0,stream>>>(d_in[idx[i]], dl[i], nl[i], probe);
    }
  }

  // --- prep ---
  k_lens<<<128,128,0,stream>>>(ti, li, nonpad, text_len, left_len);
  k_aspmean<<<128,128,0,stream>>>(ai, em_c, asp_mean);
  k_embs<<<16384,128,0,stream>>>(ti, pi, aps, em_c, pe_c, asp_mean, embs);
  k_padwih2<<<(1280*336+255)/256,256,0,stream>>>(wihf_c, wihpf);
  k_padwih2<<<(1280*336+255)/256,256,0,stream>>>(wihb_c, wihpb);
  k_padwhh2<<<(1280*320+255)/256,256,0,stream>>>(whhf_c, whh2f);
  k_padwhh2<<<(1280*320+255)/256,256,0,stream>>>(whhb_c, whh2b);
  k_biassum2<<<(1280+255)/256,256,0,stream>>>(bihf_c, bhhf_c, biasgf);
  k_biassum2<<<(1280+255)/256,256,0,stream>>>(bihb_c, bhhb_c, biasgb);
  k_biascvt<<<3,256,0,stream>>>(bq_c, bqf, 600);
  k_biascvt<<<3,256,0,stream>>>(bk_c, bkf, 600);
  k_biascvt<<<3,256,0,stream>>>(g1b_c, gc1bf, 600);
  k_biascvt<<<3,256,0,stream>>>(g2b_c, gc2bf, 600);

  // --- input projections (embs @ Wih2^T + bias), gate-packed cols, MODE 1 ---
  gemm_k<1,1><<<dim3(128,10,1),256,0,stream>>>(16384,1280,336, embs,336,0, wihpf,336,0,
        nullptr, gip_f,1280,0, biasgf,0,nullptr,nullptr);
  gemm_k<1,1><<<dim3(128,10,1),256,0,stream>>>(16384,1280,336, embs,336,0, wihpb,336,0,
        nullptr, gip_b,1280,0, biasgb,0,nullptr,nullptr);

  // --- BiLSTM: register-resident Whh, fence-free coherent h exchange ---
  hipMemsetAsync(hbuf, 0, 327680, stream);
  hipMemsetAsync(barr, 0, 2048, stream);
  lstm2_k<<<40,256,0,stream>>>(whh2f, whh2b, gip_f, gip_b, hbuf, barr, textout, text_len);

  // --- q/k projections, head-scattered (dk padded 100->104) ---
  hipMemsetAsync(qh, 0, 20447232, stream);
  hipMemsetAsync(kh, 0, 20447232, stream);
  gemm_k<1,2><<<dim3(128,5,1),256,0,stream>>>(16384,600,600, textout,600,0, wq_c,600,0,
        nullptr, qh,0,0, bqf,0,nullptr,nullptr);
  gemm_k<1,2><<<dim3(128,5,1),256,0,stream>>>(16384,600,600, textout,600,0, wk_c,600,0,
        nullptr, kh,0,0, bkf,0,nullptr,nullptr);

  // --- attention scores + mask ---
  gemm_k<1,3><<<dim3(1,1,768),256,0,stream>>>(128,128,104, qh,104,13312, kh,104,13312,
        scores, nullptr, 128, 16384, nullptr,0,nullptr, nonpad);

  // --- entmax15 (in place) ---
  k_entmax<<<98304,64,0,stream>>>(scores);

  // --- adjacency: head-mean + eye + valid; degree norms ---
  k_adjsem<<<(2097152+255)/256,256,0,stream>>>(scores, nonpad, adj_sem);
  k_dn<<<16384,64,0,stream>>>(adj_sem, dn1);
  k_dn<<<16384,64,0,stream>>>(adj_c, dn2);

  // --- SE #1 + GCN #1 (norm folded: Z = D (A (D * se * X))) ---
  k_mean<<<16384,64,0,stream>>>(textout, ymean);
  k_senet<<<128,128,0,stream>>>(ymean, sw1_c,sb1_c,sw2_c,sb2_c, nonpad, ysoft);
  k_scale2<<<(9830400+255)/256,256,0,stream>>>(textout, ysoft, dn1, se_x);
  gemm_k<0,1><<<dim3(1,5,128),256,0,stream>>>(128,600,128, adj_sem,128,16384, se_x,600,76800,
        nullptr, Zb,600,76800, nullptr,0, dn1, nullptr);
  gemm_k<0,1><<<dim3(128,5,1),256,0,stream>>>(16384,600,600, Zb,600,0, g1w_c,600,0,
        nullptr, x_sem,600,0, gc1bf,1,nullptr,nullptr);

  // --- SE #2 + GCN #2 (uses input adj) ---
  k_mean<<<16384,64,0,stream>>>(x_sem, ymean);
  k_senet<<<128,128,0,stream>>>(ymean, sw1_c,sb1_c,sw2_c,sb2_c, nonpad, ysoft);
  k_scale2<<<(9830400+255)/256,256,0,stream>>>(x_sem, ysoft, dn2, se_x);
  gemm_k<0,1><<<dim3(1,5,128),256,0,stream>>>(128,600,128, adj_c,128,16384, se_x,600,76800,
        nullptr, Zb,600,76800, nullptr,0, dn2, nullptr);
  gemm_k<0,1><<<dim3(128,5,1),256,0,stream>>>(16384,600,600, Zb,600,0, g2w_c,600,0,
        nullptr, xb,600,0, gc2bf,1,nullptr,nullptr);

  // --- biaffine pooling (only row left_len[b] of A1/A2 is ever used) ---
  k_gather<<<128,128,0,stream>>>(xb, left_len, xr);
  k_gather<<<128,128,0,stream>>>(x_sem, left_len, xsr);
  gemm_k<0,1><<<dim3(1,5,1),256,0,stream>>>(128,600,600, xr,600,0, af1_c,600,0,
        nullptr, g1,600,0, nullptr,0,nullptr,nullptr);
  gemm_k<0,1><<<dim3(1,5,1),256,0,stream>>>(128,600,600, xsr,600,0, af2_c,600,0,
        nullptr, g2,600,0, nullptr,0,nullptr,nullptr);
  k_pool<<<128,256,0,stream>>>(g1, x_sem, pooled, 0);
  k_pool<<<128,256,0,stream>>>(g2, xb, pooled, 600);

  // --- final FC (dtype-adaptive output) ---
  k_final<<<128,64,0,stream>>>(pooled, fcw_c, fcb_c, d_out, probe);
}